// Round 6
// baseline (826.422 us; speedup 1.0000x reference)
//
#include <hip/hip_runtime.h>

// Problem constants
#define T     4
#define WQ    75
#define C     640
#define HW    100
#define WAY   5
#define SHOT  5
#define SHW   500
#define SPAD  512
#define QPAD  128
#define CT    128
#define NT    5
#define NPAIR 15

// ws layout (bytes)
#define WS_COVB_OFF  0            // 20*15*16384*2 = 9,830,400 (bf16, fragment order)
#define WS_QTB_OFF   9830400      // 300*640*128*2 = 49,152,000
#define WS_QTBW_OFF  58982400     // 300*640*128*2 = 49,152,000
#define WS_STB_OFF   108134400    // 20*640*512*2  = 13,107,200

typedef __attribute__((ext_vector_type(8)))  short bfrag8;
typedef __attribute__((ext_vector_type(16))) float f32x16;

__device__ __forceinline__ unsigned short f2bf(float x) {
    unsigned int u = __float_as_uint(x);
    return (unsigned short)((u + 0x7fffu + ((u >> 16) & 1u)) >> 16);   // RNE
}
__device__ __forceinline__ float bflo(unsigned u) { return __uint_as_float(u << 16); }
__device__ __forceinline__ float bfhi(unsigned u) { return __uint_as_float(u & 0xffff0000u); }

__device__ __forceinline__ void pair_ij(int p, int& ti, int& tj) {
    int base = 0;
    #pragma unroll
    for (int a = 0; a < NT; ++a) {
        int cnt = NT - a;
        if (p < base + cnt) { ti = a; tj = a + (p - base); return; }
        base += cnt;
    }
    ti = 0; tj = 0;
}

__global__ void init_out_kernel(float* __restrict__ out, const float* __restrict__ bias) {
    int i = blockIdx.x * blockDim.x + threadIdx.x;
    if (i < T * WQ * WAY) out[i] = bias[0];
}

// Fused mean + center + bf16 pack, no register row-buffer (row is L1-hot on 2nd pass).
__global__ __launch_bounds__(256)
void meanpack_kernel(const float* __restrict__ qf, const float* __restrict__ sf,
                     const float* __restrict__ convw,
                     unsigned short* __restrict__ qtb, unsigned short* __restrict__ qtbw,
                     unsigned short* __restrict__ stb) {
    __shared__ float wl[HW];
    int tid = threadIdx.x;
    if (tid < HW) wl[tid] = convw[tid];
    __syncthreads();
    long long i = (long long)blockIdx.x * 256 + tid;
    if (i < (long long)T * WQ * C) {
        size_t r = (size_t)i;                       // tq*C + c
        const float4* p = (const float4*)(qf + r * HW);
        float accm = 0.f;
        #pragma unroll
        for (int f = 0; f < 25; ++f) { float4 v = p[f]; accm += v.x + v.y + v.z + v.w; }
        float m = accm * (1.0f / HW);
        #pragma unroll
        for (int oct = 0; oct < QPAD / 8; ++oct) {
            unsigned short ob[8] __attribute__((aligned(16)));
            unsigned short ow[8] __attribute__((aligned(16)));
            if (oct < 12) {
                float4 v0 = p[oct * 2], v1 = p[oct * 2 + 1];
                float vs[8] = {v0.x, v0.y, v0.z, v0.w, v1.x, v1.y, v1.z, v1.w};
                #pragma unroll
                for (int j = 0; j < 8; ++j) {
                    float v = vs[j] - m;
                    ob[j] = f2bf(v); ow[j] = f2bf(v * wl[oct * 8 + j]);
                }
            } else if (oct == 12) {
                float4 v0 = p[24];
                float vs[4] = {v0.x, v0.y, v0.z, v0.w};
                #pragma unroll
                for (int j = 0; j < 4; ++j) {
                    float v = vs[j] - m;
                    ob[j] = f2bf(v); ow[j] = f2bf(v * wl[96 + j]);
                }
                #pragma unroll
                for (int j = 4; j < 8; ++j) { ob[j] = 0; ow[j] = 0; }
            } else {
                #pragma unroll
                for (int j = 0; j < 8; ++j) { ob[j] = 0; ow[j] = 0; }
            }
            *(uint4*)(qtb  + r * QPAD + oct * 8) = *(uint4*)ob;
            *(uint4*)(qtbw + r * QPAD + oct * 8) = *(uint4*)ow;
        }
    } else if (i < (long long)T * WQ * C + (long long)T * WAY * C) {
        int j = (int)(i - (long long)T * WQ * C);   // tw*C + c
        int tw = j / C, c = j % C;
        float accm = 0.f;
        #pragma unroll
        for (int sh = 0; sh < SHOT; ++sh) {
            const float4* p = (const float4*)(sf + ((size_t)(tw * SHOT + sh) * C + c) * HW);
            #pragma unroll
            for (int f = 0; f < 25; ++f) { float4 v = p[f]; accm += v.x + v.y + v.z + v.w; }
        }
        float m = accm * (1.0f / SHW);
        for (int oct = 0; oct < SPAD / 8; ++oct) {
            unsigned short ob[8] __attribute__((aligned(16)));
            #pragma unroll
            for (int j2 = 0; j2 < 8; ++j2) {
                int mm = oct * 8 + j2; float v = 0.f;
                if (mm < SHW) {
                    int sh = mm / HW, n = mm % HW;
                    v = sf[((size_t)(tw * SHOT + sh) * C + c) * HW + n] - m;
                }
                ob[j2] = f2bf(v);
            }
            *(uint4*)(stb + (size_t)j * SPAD + oct * 8) = *(uint4*)ob;
        }
    }
}

// ---- staging via global_load_lds (wave-uniform base + lane*16B), linear LDS layout ----
// Plane: 128 rows x 32 shorts (64 B/row). Per wave: 2 segments of 16 rows (1 KB each).
__device__ __forceinline__ void stage_async(unsigned short* ldsbase, const unsigned short* src,
                                            int rowlen, int ch, int wave, int lane) {
    #pragma unroll
    for (int j = 0; j < 2; ++j) {
        int seg = wave * 2 + j;                          // 0..7
        int row = seg * 16 + (lane >> 2);
        const unsigned short* g = src + (size_t)row * rowlen + ch * 32 + (lane & 3) * 8;
        unsigned short* l = ldsbase + seg * 512 + lane * 8;   // base + lane*16B
        __builtin_amdgcn_global_load_lds(
            (const __attribute__((address_space(1))) void*)g,
            (__attribute__((address_space(3))) void*)l, 16, 0, 0);
    }
}

// MFMA over one 32-k chunk; frag reads at 64 B row stride = 2-way LDS alias (free).
__device__ __forceinline__ void mfma_chunk(const unsigned short* Al, const unsigned short* Bl,
                                           f32x16* acc, int rA, int rB, int lh) {
    #pragma unroll
    for (int s = 0; s < 2; ++s) {
        int sw = (s * 2 + lh) * 8;                       // k-octet within row
        bfrag8 a0 = *(const bfrag8*)&Al[(size_t)rA * 32 + sw];
        bfrag8 a1 = *(const bfrag8*)&Al[(size_t)(rA + 32) * 32 + sw];
        bfrag8 b0 = *(const bfrag8*)&Bl[(size_t)rB * 32 + sw];
        bfrag8 b1 = *(const bfrag8*)&Bl[(size_t)(rB + 32) * 32 + sw];
        acc[0] = __builtin_amdgcn_mfma_f32_32x32x16_bf16(a0, b0, acc[0], 0, 0, 0);
        acc[1] = __builtin_amdgcn_mfma_f32_32x32x16_bf16(a0, b1, acc[1], 0, 0, 0);
        acc[2] = __builtin_amdgcn_mfma_f32_32x32x16_bf16(a1, b0, acc[2], 0, 0, 0);
        acc[3] = __builtin_amdgcn_mfma_f32_32x32x16_bf16(a1, b1, acc[3], 0, 0, 0);
    }
}

// Cov tiles -> bf16 fragment order. grid = (NPAIR, T*WAY)
__global__ __launch_bounds__(256, 4)
void cov_kernel(const unsigned short* __restrict__ stb, unsigned short* __restrict__ covb) {
    __shared__ unsigned short Al[4096], Bl[4096];
    int p = blockIdx.x, tw = blockIdx.y;
    int ti, tj; pair_ij(p, ti, tj);
    int tid = threadIdx.x, lane = tid & 63, wave = tid >> 6;
    int qm = wave & 1, qn = wave >> 1, lh = lane >> 5, ls = lane & 31;
    int rA = qm * 64 + ls, rB = qn * 64 + ls;
    const unsigned short* Ab = stb + ((size_t)tw * C + ti * CT) * SPAD;
    const unsigned short* Bb = stb + ((size_t)tw * C + tj * CT) * SPAD;

    f32x16 acc[4];
    #pragma unroll
    for (int b = 0; b < 4; ++b)
        #pragma unroll
        for (int e = 0; e < 16; ++e) acc[b][e] = 0.f;

    for (int ch = 0; ch < SPAD / 32; ++ch) {
        __syncthreads();
        stage_async(Al, Ab, SPAD, ch, wave, lane);
        stage_async(Bl, Bb, SPAD, ch, wave, lane);
        __syncthreads();
        mfma_chunk(Al, Bl, acc, rA, rB, lh);
    }

    const float inv = 1.0f / (HW - 1);
    unsigned short* cb = covb + ((size_t)tw * NPAIR + p) * 16384;
    #pragma unroll
    for (int b = 0; b < 4; ++b) {
        unsigned ow[8];
        #pragma unroll
        for (int wd = 0; wd < 8; ++wd)
            ow[wd] = (unsigned)f2bf(acc[b][2 * wd] * inv)
                   | ((unsigned)f2bf(acc[b][2 * wd + 1] * inv) << 16);
        size_t off = (size_t)((wave * 4 + b) * 64 + lane) * 16;
        *(uint4*)(cb + off)     = *(uint4*)&ow[0];
        *(uint4*)(cb + off + 8) = *(uint4*)&ow[4];
    }
}

// Fused M-build (MFMA) + bf16 cov Frobenius dot. grid = (qg, p, t); 5 queries/block.
__global__ __launch_bounds__(256, 4)
void score_kernel(const unsigned short* __restrict__ qtb, const unsigned short* __restrict__ qtbw,
                  const unsigned short* __restrict__ covb, float* __restrict__ out) {
    __shared__ unsigned short Al[4096], Bl[4096];
    __shared__ float red[4][WAY];
    int qg = blockIdx.x, p = blockIdx.y, t = blockIdx.z;
    int ti, tj; pair_ij(p, ti, tj);
    int tid = threadIdx.x, lane = tid & 63, wave = tid >> 6;
    int qm = wave & 1, qn = wave >> 1, lh = lane >> 5, ls = lane & 31;
    int rA = qm * 64 + ls, rB = qn * 64 + ls;
    float mult = (ti == tj) ? 1.0f : 2.0f;
    const unsigned short* cbase = covb + ((size_t)(t * WAY) * NPAIR + p) * 16384;

    for (int qi = 0; qi < 5; ++qi) {
        int q = qg * 5 + qi;
        const unsigned short* Ab = qtbw + ((size_t)(t * WQ + q) * C + ti * CT) * QPAD;
        const unsigned short* Bb = qtb  + ((size_t)(t * WQ + q) * C + tj * CT) * QPAD;

        f32x16 acc[4];
        #pragma unroll
        for (int b = 0; b < 4; ++b)
            #pragma unroll
            for (int e = 0; e < 16; ++e) acc[b][e] = 0.f;

        for (int ch = 0; ch < QPAD / 32; ++ch) {
            __syncthreads();                 // protects LDS + red[] from previous use
            stage_async(Al, Ab, QPAD, ch, wave, lane);
            stage_async(Bl, Bb, QPAD, ch, wave, lane);
            __syncthreads();
            mfma_chunk(Al, Bl, acc, rA, rB, lh);
        }

        // Frobenius dot with 5 ways' bf16 cov tiles (fragment order => coalesced)
        float sums[WAY];
        #pragma unroll
        for (int w = 0; w < WAY; ++w) {
            const unsigned short* cb = cbase + (size_t)w * NPAIR * 16384;
            float s = 0.f;
            #pragma unroll
            for (int b = 0; b < 4; ++b) {
                size_t off = (size_t)((wave * 4 + b) * 64 + lane) * 16;
                uint4 u0 = *(const uint4*)(cb + off);
                uint4 u1 = *(const uint4*)(cb + off + 8);
                unsigned uw[8] = {u0.x, u0.y, u0.z, u0.w, u1.x, u1.y, u1.z, u1.w};
                #pragma unroll
                for (int wd = 0; wd < 8; ++wd)
                    s += bflo(uw[wd]) * acc[b][2 * wd] + bfhi(uw[wd]) * acc[b][2 * wd + 1];
            }
            sums[w] = s * mult;
        }

        #pragma unroll
        for (int w = 0; w < WAY; ++w) {
            float v = sums[w];
            #pragma unroll
            for (int off = 32; off > 0; off >>= 1) v += __shfl_down(v, off);
            if (lane == 0) red[wave][w] = v;
        }
        __syncthreads();
        if (tid < WAY) {
            float tot = red[0][tid] + red[1][tid] + red[2][tid] + red[3][tid];
            atomicAdd(&out[(size_t)(t * WQ + q) * WAY + tid], tot);
        }
    }
}

extern "C" void kernel_launch(void* const* d_in, const int* in_sizes, int n_in,
                              void* d_out, int out_size, void* d_ws, size_t ws_size,
                              hipStream_t stream) {
    const float* qf = (const float*)d_in[0];   // (4,75,640,10,10)
    const float* sf = (const float*)d_in[1];   // (4,25,640,10,10)
    const float* cw = (const float*)d_in[2];   // (1,1,100)
    const float* cb = (const float*)d_in[3];   // (1,)
    float* out = (float*)d_out;                // (4,75,5)

    unsigned short* covb = (unsigned short*)((char*)d_ws + WS_COVB_OFF);
    unsigned short* qtb  = (unsigned short*)((char*)d_ws + WS_QTB_OFF);
    unsigned short* qtbw = (unsigned short*)((char*)d_ws + WS_QTBW_OFF);
    unsigned short* stb  = (unsigned short*)((char*)d_ws + WS_STB_OFF);

    init_out_kernel<<<(T * WQ * WAY + 255) / 256, 256, 0, stream>>>(out, cb);
    meanpack_kernel<<<800, 256, 0, stream>>>(qf, sf, cw, qtb, qtbw, stb);
    cov_kernel<<<dim3(NPAIR, T * WAY), 256, 0, stream>>>(stb, covb);
    score_kernel<<<dim3(WQ / 5, NPAIR, T), 256, 0, stream>>>(qtb, qtbw, covb, out);
}

// Round 7
// 290.890 us; speedup vs baseline: 2.8410x; 2.8410x over previous
//
#include <hip/hip_runtime.h>

// Problem constants
#define T     4
#define WQ    75
#define C     640
#define HW    100
#define WAY   5
#define SHOT  5
#define NT    5
#define NPAIR 15

// bf16 tile storage: octet-transposed fragment-friendly layout
//   q tiles:  [tq][tile(5)][oct(16)][row(128)][8]  -> 16384 shorts/tile
//   s tiles:  [tw][tile(5)][oct(80)][row(128)][8]  -> 81920 shorts/tile (per-shot 128-k pad)
#define QTS   16384
#define STS   81920

// ws layout (bytes)
#define WS_COVB_OFF  0            // 20*15*16384*2 = 9,830,400 (bf16, fragment order)
#define WS_QTB_OFF   9830400      // 300*5*16384*2 = 49,152,000
#define WS_QTBW_OFF  58982400     // 300*5*16384*2 = 49,152,000
#define WS_STB_OFF   108134400    // 20*5*81920*2  = 16,384,000

typedef __attribute__((ext_vector_type(8)))  short bfrag8;
typedef __attribute__((ext_vector_type(16))) float f32x16;

__device__ __forceinline__ unsigned short f2bf(float x) {
    unsigned int u = __float_as_uint(x);
    return (unsigned short)((u + 0x7fffu + ((u >> 16) & 1u)) >> 16);   // RNE
}
__device__ __forceinline__ float bflo(unsigned u) { return __uint_as_float(u << 16); }
__device__ __forceinline__ float bfhi(unsigned u) { return __uint_as_float(u & 0xffff0000u); }

__device__ __forceinline__ void pair_ij(int p, int& ti, int& tj) {
    int base = 0;
    #pragma unroll
    for (int a = 0; a < NT; ++a) {
        int cnt = NT - a;
        if (p < base + cnt) { ti = a; tj = a + (p - base); return; }
        base += cnt;
    }
    ti = 0; tj = 0;
}

__global__ void init_out_kernel(float* __restrict__ out, const float* __restrict__ bias) {
    int i = blockIdx.x * blockDim.x + threadIdx.x;
    if (i < T * WQ * WAY) out[i] = bias[0];
}

// ---------- prep: cooperative, coalesced mean+center+pack ----------
// One block = 64 source rows (contiguous 6400 floats in global).
// qpack: grid (10 cblocks, 300 tq) -> qtb + qtbw
__global__ __launch_bounds__(256)
void qpack_kernel(const float* __restrict__ qf, const float* __restrict__ convw,
                  unsigned short* __restrict__ qtb, unsigned short* __restrict__ qtbw) {
    __shared__ float ld[64 * 101];
    __shared__ float wl[HW];
    __shared__ float mpart[64][5];
    __shared__ float mean[64];
    int cb = blockIdx.x, tq = blockIdx.y;
    int tid = threadIdx.x;
    if (tid < HW) wl[tid] = convw[tid];
    const float* src = qf + ((size_t)tq * C + cb * 64) * HW;
    #pragma unroll
    for (int it = 0; it < 7; ++it) {
        int idx = tid + it * 256;
        if (idx < 1600) {
            float4 v = ((const float4*)src)[idx];
            int f = idx * 4;
            float vs[4] = {v.x, v.y, v.z, v.w};
            #pragma unroll
            for (int j = 0; j < 4; ++j) {
                int ff = f + j;
                ld[(ff / HW) * 101 + (ff % HW)] = vs[j];
            }
        }
    }
    __syncthreads();
    {
        int row = tid & 63, part = tid >> 6;
        float ps = 0.f;
        #pragma unroll
        for (int i = 0; i < 25; ++i) ps += ld[row * 101 + part * 25 + i];
        mpart[row][part] = ps;
    }
    __syncthreads();
    if (tid < 64) mean[tid] = (mpart[tid][0] + mpart[tid][1] + mpart[tid][2] + mpart[tid][3]) * (1.0f / HW);
    __syncthreads();
    int tile = cb >> 1;
    #pragma unroll
    for (int it = 0; it < 4; ++it) {
        int task = tid + it * 256;              // 1024 tasks: row(64) x oct(16)
        int row = task & 63, oct = task >> 6;
        float m = mean[row];
        unsigned short ob[8] __attribute__((aligned(16)));
        unsigned short ow[8] __attribute__((aligned(16)));
        #pragma unroll
        for (int j = 0; j < 8; ++j) {
            int n = oct * 8 + j;
            float v = (n < HW) ? (ld[row * 101 + n] - m) : 0.f;
            float w = (n < HW) ? wl[n] : 0.f;
            ob[j] = f2bf(v); ow[j] = f2bf(v * w);
        }
        int trow = ((cb & 1) << 6) + row;
        size_t dst = ((((size_t)tq * NT + tile) * 16 + oct) * 128 + trow) * 8;
        *(uint4*)(qtb + dst)  = *(uint4*)ob;
        *(uint4*)(qtbw + dst) = *(uint4*)ow;
    }
}

// spack: grid (10 cblocks, 20 tw) -> stb (per-shot 128-k pad, no weights)
__global__ __launch_bounds__(256)
void spack_kernel(const float* __restrict__ sf, unsigned short* __restrict__ stb) {
    __shared__ float ld[64 * 101];
    __shared__ float mpart[64][5];
    __shared__ float mean[64];
    int cb = blockIdx.x, tw = blockIdx.y;
    int tid = threadIdx.x;
    int row = tid & 63, part = tid >> 6;
    float ps = 0.f;
    for (int sh = 0; sh < SHOT; ++sh) {
        const float* src = sf + ((size_t)(tw * SHOT + sh) * C + cb * 64) * HW;
        __syncthreads();
        #pragma unroll
        for (int it = 0; it < 7; ++it) {
            int idx = tid + it * 256;
            if (idx < 1600) {
                float4 v = ((const float4*)src)[idx];
                int f = idx * 4;
                float vs[4] = {v.x, v.y, v.z, v.w};
                #pragma unroll
                for (int j = 0; j < 4; ++j) {
                    int ff = f + j;
                    ld[(ff / HW) * 101 + (ff % HW)] = vs[j];
                }
            }
        }
        __syncthreads();
        #pragma unroll
        for (int i = 0; i < 25; ++i) ps += ld[row * 101 + part * 25 + i];
    }
    mpart[row][part] = ps;
    __syncthreads();
    if (tid < 64) mean[tid] = (mpart[tid][0] + mpart[tid][1] + mpart[tid][2] + mpart[tid][3]) * (1.0f / (SHOT * HW));
    int tile = cb >> 1;
    int trowbase = (cb & 1) << 6;
    for (int sh = 0; sh < SHOT; ++sh) {
        const float* src = sf + ((size_t)(tw * SHOT + sh) * C + cb * 64) * HW;
        __syncthreads();
        #pragma unroll
        for (int it = 0; it < 7; ++it) {
            int idx = tid + it * 256;
            if (idx < 1600) {
                float4 v = ((const float4*)src)[idx];
                int f = idx * 4;
                float vs[4] = {v.x, v.y, v.z, v.w};
                #pragma unroll
                for (int j = 0; j < 4; ++j) {
                    int ff = f + j;
                    ld[(ff / HW) * 101 + (ff % HW)] = vs[j];
                }
            }
        }
        __syncthreads();
        #pragma unroll
        for (int it = 0; it < 4; ++it) {
            int task = tid + it * 256;
            int r2 = task & 63, oct = task >> 6;
            float m = mean[r2];
            unsigned short ob[8] __attribute__((aligned(16)));
            #pragma unroll
            for (int j = 0; j < 8; ++j) {
                int n = oct * 8 + j;
                ob[j] = (n < HW) ? f2bf(ld[r2 * 101 + n] - m) : (unsigned short)0;
            }
            size_t dst = ((((size_t)tw * NT + tile) * 80 + sh * 16 + oct) * 128 + trowbase + r2) * 8;
            *(uint4*)(stb + dst) = *(uint4*)ob;
        }
    }
}

// ---------- async staging: 16 KB chunk (8 octets x 128 rows), contiguous in global ----------
__device__ __forceinline__ void stage64(unsigned short* lds, const unsigned short* src,
                                        int wave, int lane) {
    #pragma unroll
    for (int j = 0; j < 4; ++j) {
        int seg = wave * 4 + j;                          // 16 x 1KB segments
        const unsigned short* g = src + seg * 512 + lane * 8;
        unsigned short* l = lds + seg * 512 + lane * 8;
        __builtin_amdgcn_global_load_lds(
            (const __attribute__((address_space(1))) void*)g,
            (__attribute__((address_space(3))) void*)l, 16, 0, 0);
    }
}

// 64-k chunk MFMA; frag reads lane-contiguous (conflict-free)
__device__ __forceinline__ void mfma_chunk64(const unsigned short* Al, const unsigned short* Bl,
                                             f32x16* acc, int rA, int rB, int lh) {
    #pragma unroll
    for (int s = 0; s < 4; ++s) {
        int oc = s * 2 + lh;
        const unsigned short* ab = Al + (size_t)oc * 1024;
        const unsigned short* bb = Bl + (size_t)oc * 1024;
        bfrag8 a0 = *(const bfrag8*)&ab[rA * 8];
        bfrag8 a1 = *(const bfrag8*)&ab[(rA + 32) * 8];
        bfrag8 b0 = *(const bfrag8*)&bb[rB * 8];
        bfrag8 b1 = *(const bfrag8*)&bb[(rB + 32) * 8];
        acc[0] = __builtin_amdgcn_mfma_f32_32x32x16_bf16(a0, b0, acc[0], 0, 0, 0);
        acc[1] = __builtin_amdgcn_mfma_f32_32x32x16_bf16(a0, b1, acc[1], 0, 0, 0);
        acc[2] = __builtin_amdgcn_mfma_f32_32x32x16_bf16(a1, b0, acc[2], 0, 0, 0);
        acc[3] = __builtin_amdgcn_mfma_f32_32x32x16_bf16(a1, b1, acc[3], 0, 0, 0);
    }
}

// Cov tiles -> bf16 fragment order. grid = (NPAIR, T*WAY)
__global__ __launch_bounds__(256, 3)
void cov_kernel(const unsigned short* __restrict__ stb, unsigned short* __restrict__ covb) {
    __shared__ unsigned short Al[8192], Bl[8192];
    int p = blockIdx.x, tw = blockIdx.y;
    int ti, tj; pair_ij(p, ti, tj);
    int tid = threadIdx.x, lane = tid & 63, wave = tid >> 6;
    int qm = wave & 1, qn = wave >> 1, lh = lane >> 5, ls = lane & 31;
    int rA = qm * 64 + ls, rB = qn * 64 + ls;
    const unsigned short* Ab = stb + ((size_t)tw * NT + ti) * STS;
    const unsigned short* Bb = stb + ((size_t)tw * NT + tj) * STS;

    f32x16 acc[4];
    #pragma unroll
    for (int b = 0; b < 4; ++b)
        #pragma unroll
        for (int e = 0; e < 16; ++e) acc[b][e] = 0.f;

    for (int ch = 0; ch < 10; ++ch) {
        __syncthreads();
        stage64(Al, Ab + ch * 8192, wave, lane);
        stage64(Bl, Bb + ch * 8192, wave, lane);
        __syncthreads();
        mfma_chunk64(Al, Bl, acc, rA, rB, lh);
    }

    const float inv = 1.0f / (HW - 1);
    unsigned short* cb = covb + ((size_t)tw * NPAIR + p) * 16384;
    #pragma unroll
    for (int b = 0; b < 4; ++b) {
        unsigned ow[8];
        #pragma unroll
        for (int wd = 0; wd < 8; ++wd)
            ow[wd] = (unsigned)f2bf(acc[b][2 * wd] * inv)
                   | ((unsigned)f2bf(acc[b][2 * wd + 1] * inv) << 16);
        size_t off = (size_t)((wave * 4 + b) * 64 + lane) * 16;
        *(uint4*)(cb + off)     = *(uint4*)&ow[0];
        *(uint4*)(cb + off + 8) = *(uint4*)&ow[4];
    }
}

// Fused M-build (MFMA) + bf16 cov dot. grid = (qg=15, p=15, t=4).
__global__ __launch_bounds__(256, 3)
void score_kernel(const unsigned short* __restrict__ qtb, const unsigned short* __restrict__ qtbw,
                  const unsigned short* __restrict__ covb, float* __restrict__ out) {
    __shared__ unsigned short Al[8192], Bl[8192];
    __shared__ float red[4][WAY];
    int qg = blockIdx.x, p = blockIdx.y, t = blockIdx.z;
    int ti, tj; pair_ij(p, ti, tj);
    int tid = threadIdx.x, lane = tid & 63, wave = tid >> 6;
    int qm = wave & 1, qn = wave >> 1, lh = lane >> 5, ls = lane & 31;
    int rA = qm * 64 + ls, rB = qn * 64 + ls;
    float mult = (ti == tj) ? 1.0f : 2.0f;
    const unsigned short* cbase = covb + ((size_t)(t * WAY) * NPAIR + p) * 16384;

    for (int qi = 0; qi < 5; ++qi) {
        int q = qg * 5 + qi;
        const unsigned short* Ab = qtbw + ((size_t)(t * WQ + q) * NT + ti) * QTS;
        const unsigned short* Bb = qtb  + ((size_t)(t * WQ + q) * NT + tj) * QTS;

        f32x16 acc[4];
        #pragma unroll
        for (int b = 0; b < 4; ++b)
            #pragma unroll
            for (int e = 0; e < 16; ++e) acc[b][e] = 0.f;

        #pragma unroll
        for (int ch = 0; ch < 2; ++ch) {
            __syncthreads();                 // also protects red[] reuse
            stage64(Al, Ab + ch * 8192, wave, lane);
            stage64(Bl, Bb + ch * 8192, wave, lane);
            __syncthreads();
            mfma_chunk64(Al, Bl, acc, rA, rB, lh);
        }

        // per-way dot + immediate reduce (unroll 1 keeps register pressure low: no spills)
        #pragma unroll 1
        for (int w = 0; w < WAY; ++w) {
            const unsigned short* cb = cbase + (size_t)w * NPAIR * 16384;
            float s = 0.f;
            #pragma unroll
            for (int b = 0; b < 4; ++b) {
                size_t off = (size_t)((wave * 4 + b) * 64 + lane) * 16;
                uint4 u0 = *(const uint4*)(cb + off);
                uint4 u1 = *(const uint4*)(cb + off + 8);
                unsigned uw[8] = {u0.x, u0.y, u0.z, u0.w, u1.x, u1.y, u1.z, u1.w};
                #pragma unroll
                for (int wd = 0; wd < 8; ++wd)
                    s += bflo(uw[wd]) * acc[b][2 * wd] + bfhi(uw[wd]) * acc[b][2 * wd + 1];
            }
            float v = s * mult;
            #pragma unroll
            for (int off2 = 32; off2 > 0; off2 >>= 1) v += __shfl_down(v, off2);
            if (lane == 0) red[wave][w] = v;
        }
        __syncthreads();
        if (tid < WAY) {
            float tot = red[0][tid] + red[1][tid] + red[2][tid] + red[3][tid];
            atomicAdd(&out[(size_t)(t * WQ + q) * WAY + tid], tot);
        }
    }
}

extern "C" void kernel_launch(void* const* d_in, const int* in_sizes, int n_in,
                              void* d_out, int out_size, void* d_ws, size_t ws_size,
                              hipStream_t stream) {
    const float* qf = (const float*)d_in[0];   // (4,75,640,10,10)
    const float* sf = (const float*)d_in[1];   // (4,25,640,10,10)
    const float* cw = (const float*)d_in[2];   // (1,1,100)
    const float* cb = (const float*)d_in[3];   // (1,)
    float* out = (float*)d_out;                // (4,75,5)

    unsigned short* covb = (unsigned short*)((char*)d_ws + WS_COVB_OFF);
    unsigned short* qtb  = (unsigned short*)((char*)d_ws + WS_QTB_OFF);
    unsigned short* qtbw = (unsigned short*)((char*)d_ws + WS_QTBW_OFF);
    unsigned short* stb  = (unsigned short*)((char*)d_ws + WS_STB_OFF);

    init_out_kernel<<<(T * WQ * WAY + 255) / 256, 256, 0, stream>>>(out, cb);
    qpack_kernel<<<dim3(10, T * WQ), 256, 0, stream>>>(qf, cw, qtb, qtbw);
    spack_kernel<<<dim3(10, T * WAY), 256, 0, stream>>>(sf, stb);
    cov_kernel<<<dim3(NPAIR, T * WAY), 256, 0, stream>>>(stb, covb);
    score_kernel<<<dim3(WQ / 5, NPAIR, T), 256, 0, stream>>>(qtb, qtbw, covb, out);
}

// Round 8
// 284.715 us; speedup vs baseline: 2.9026x; 1.0217x over previous
//
#include <hip/hip_runtime.h>

// Problem constants
#define T     4
#define WQ    75
#define C     640
#define HW    100
#define WAY   5
#define SHOT  5
#define NT    5
#define NPAIR 15

// q tiles: [tq][tile(5)][oct(14)][row(128)][8] bf16; octets 12/13 partially/fully zero
#define QOCT  14
#define QTS   (QOCT*128*8)        // 14336 shorts = 28 KB
// s tiles: [tw][tile(5)][oct(80)][row(128)][8] (16 oct/shot, zero-padded) — unchanged from R7
#define STS   81920

// ws layout (bytes)
#define WS_COVB_OFF  0            // 20*15*16384*2 = 9,830,400 (bf16, fragment order)
#define WS_QTB_OFF   9830400      // 300*5*14336*2 = 43,008,000
#define WS_STB_OFF   52838400     // 20*5*81920*2  = 16,384,000

typedef __attribute__((ext_vector_type(8)))  short bfrag8;
typedef __attribute__((ext_vector_type(16))) float f32x16;

__device__ __forceinline__ unsigned short f2bf(float x) {
    unsigned int u = __float_as_uint(x);
    return (unsigned short)((u + 0x7fffu + ((u >> 16) & 1u)) >> 16);   // RNE
}
__device__ __forceinline__ float bflo(unsigned u) { return __uint_as_float(u << 16); }
__device__ __forceinline__ float bfhi(unsigned u) { return __uint_as_float(u & 0xffff0000u); }

__device__ __forceinline__ void pair_ij(int p, int& ti, int& tj) {
    int base = 0;
    #pragma unroll
    for (int a = 0; a < NT; ++a) {
        int cnt = NT - a;
        if (p < base + cnt) { ti = a; tj = a + (p - base); return; }
        base += cnt;
    }
    ti = 0; tj = 0;
}

// ---------- merged prep: out-init + qpack + spack in one launch ----------
// grid: [0,3000) qpack (cb=bid%10, tq=bid/10); [3000,3200) spack; 3200 init.
__global__ __launch_bounds__(256)
void prep_kernel(const float* __restrict__ qf, const float* __restrict__ sf,
                 const float* __restrict__ bias,
                 unsigned short* __restrict__ qtb, unsigned short* __restrict__ stb,
                 float* __restrict__ out) {
    __shared__ float ld[64 * 101];
    __shared__ float mpart[64][4];
    __shared__ float mean[64];
    int bid = blockIdx.x, tid = threadIdx.x;

    if (bid < 3000) {
        int cb = bid % 10, tq = bid / 10;
        const float* src = qf + ((size_t)tq * C + cb * 64) * HW;
        #pragma unroll
        for (int it = 0; it < 7; ++it) {
            int idx = tid + it * 256;
            if (idx < 1600) {
                float4 v = ((const float4*)src)[idx];
                int f = idx * 4;
                float vs[4] = {v.x, v.y, v.z, v.w};
                #pragma unroll
                for (int j = 0; j < 4; ++j) {
                    int ff = f + j;
                    ld[(ff / HW) * 101 + (ff % HW)] = vs[j];
                }
            }
        }
        __syncthreads();
        {
            int row = tid & 63, part = tid >> 6;
            float ps = 0.f;
            #pragma unroll
            for (int i = 0; i < 25; ++i) ps += ld[row * 101 + part * 25 + i];
            mpart[row][part] = ps;
        }
        __syncthreads();
        if (tid < 64) mean[tid] = (mpart[tid][0] + mpart[tid][1] + mpart[tid][2] + mpart[tid][3]) * (1.0f / HW);
        __syncthreads();
        int tile = cb >> 1, trowbase = (cb & 1) << 6;
        #pragma unroll
        for (int it = 0; it < 4; ++it) {
            int task = tid + it * 256;              // 896 tasks: row(64) x oct(14)
            if (task < 64 * QOCT) {
                int row = task & 63, oct = task >> 6;
                float m = mean[row];
                unsigned short ob[8] __attribute__((aligned(16)));
                #pragma unroll
                for (int j = 0; j < 8; ++j) {
                    int n = oct * 8 + j;
                    ob[j] = (n < HW) ? f2bf(ld[row * 101 + n] - m) : (unsigned short)0;
                }
                size_t dst = ((((size_t)tq * NT + tile) * QOCT + oct) * 128 + trowbase + row) * 8;
                *(uint4*)(qtb + dst) = *(uint4*)ob;
            }
        }
    } else if (bid < 3200) {
        int idx2 = bid - 3000;
        int cb = idx2 % 10, tw = idx2 / 10;
        int row = tid & 63, part = tid >> 6;
        float ps = 0.f;
        for (int sh = 0; sh < SHOT; ++sh) {
            const float* src = sf + ((size_t)(tw * SHOT + sh) * C + cb * 64) * HW;
            __syncthreads();
            #pragma unroll
            for (int it = 0; it < 7; ++it) {
                int idx = tid + it * 256;
                if (idx < 1600) {
                    float4 v = ((const float4*)src)[idx];
                    int f = idx * 4;
                    float vs[4] = {v.x, v.y, v.z, v.w};
                    #pragma unroll
                    for (int j = 0; j < 4; ++j) {
                        int ff = f + j;
                        ld[(ff / HW) * 101 + (ff % HW)] = vs[j];
                    }
                }
            }
            __syncthreads();
            #pragma unroll
            for (int i = 0; i < 25; ++i) ps += ld[row * 101 + part * 25 + i];
        }
        mpart[row][part] = ps;
        __syncthreads();
        if (tid < 64) mean[tid] = (mpart[tid][0] + mpart[tid][1] + mpart[tid][2] + mpart[tid][3]) * (1.0f / (SHOT * HW));
        int tile = cb >> 1, trowbase = (cb & 1) << 6;
        for (int sh = 0; sh < SHOT; ++sh) {
            const float* src = sf + ((size_t)(tw * SHOT + sh) * C + cb * 64) * HW;
            __syncthreads();
            #pragma unroll
            for (int it = 0; it < 7; ++it) {
                int idx = tid + it * 256;
                if (idx < 1600) {
                    float4 v = ((const float4*)src)[idx];
                    int f = idx * 4;
                    float vs[4] = {v.x, v.y, v.z, v.w};
                    #pragma unroll
                    for (int j = 0; j < 4; ++j) {
                        int ff = f + j;
                        ld[(ff / HW) * 101 + (ff % HW)] = vs[j];
                    }
                }
            }
            __syncthreads();
            #pragma unroll
            for (int it = 0; it < 4; ++it) {
                int task = tid + it * 256;
                int r2 = task & 63, oct = task >> 6;
                float m = mean[r2];
                unsigned short ob[8] __attribute__((aligned(16)));
                #pragma unroll
                for (int j = 0; j < 8; ++j) {
                    int n = oct * 8 + j;
                    ob[j] = (n < HW) ? f2bf(ld[r2 * 101 + n] - m) : (unsigned short)0;
                }
                size_t dst = ((((size_t)tw * NT + tile) * 80 + sh * 16 + oct) * 128 + trowbase + r2) * 8;
                *(uint4*)(stb + dst) = *(uint4*)ob;
            }
        }
    } else {
        float b = bias[0];
        for (int i = tid; i < T * WQ * WAY; i += 256) out[i] = b;
    }
}

// ---------- async staging: spw 1KB-segments per wave, contiguous in global ----------
__device__ __forceinline__ void stageN(unsigned short* lds, const unsigned short* src,
                                       int spw, int wave, int lane) {
    for (int j = 0; j < spw; ++j) {
        int seg = wave * spw + j;
        __builtin_amdgcn_global_load_lds(
            (const __attribute__((address_space(1))) void*)(src + seg * 512 + lane * 8),
            (__attribute__((address_space(3))) void*)(lds + seg * 512 + lane * 8), 16, 0, 0);
    }
}

// 64-k chunk MFMA (cov path, unweighted), as R7
__device__ __forceinline__ void mfma_chunk64(const unsigned short* Al, const unsigned short* Bl,
                                             f32x16* acc, int rA, int rB, int lh) {
    #pragma unroll
    for (int s = 0; s < 4; ++s) {
        int oc = s * 2 + lh;
        const unsigned short* ab = Al + (size_t)oc * 1024;
        const unsigned short* bb = Bl + (size_t)oc * 1024;
        bfrag8 a0 = *(const bfrag8*)&ab[rA * 8];
        bfrag8 a1 = *(const bfrag8*)&ab[(rA + 32) * 8];
        bfrag8 b0 = *(const bfrag8*)&bb[rB * 8];
        bfrag8 b1 = *(const bfrag8*)&bb[(rB + 32) * 8];
        acc[0] = __builtin_amdgcn_mfma_f32_32x32x16_bf16(a0, b0, acc[0], 0, 0, 0);
        acc[1] = __builtin_amdgcn_mfma_f32_32x32x16_bf16(a0, b1, acc[1], 0, 0, 0);
        acc[2] = __builtin_amdgcn_mfma_f32_32x32x16_bf16(a1, b0, acc[2], 0, 0, 0);
        acc[3] = __builtin_amdgcn_mfma_f32_32x32x16_bf16(a1, b1, acc[3], 0, 0, 0);
    }
}

// Cov tiles -> bf16 fragment order. grid = (NPAIR, T*WAY). (unchanged from R7)
__global__ __launch_bounds__(256, 3)
void cov_kernel(const unsigned short* __restrict__ stb, unsigned short* __restrict__ covb) {
    __shared__ unsigned short Al[8192], Bl[8192];
    int p = blockIdx.x, tw = blockIdx.y;
    int ti, tj; pair_ij(p, ti, tj);
    int tid = threadIdx.x, lane = tid & 63, wave = tid >> 6;
    int qm = wave & 1, qn = wave >> 1, lh = lane >> 5, ls = lane & 31;
    int rA = qm * 64 + ls, rB = qn * 64 + ls;
    const unsigned short* Ab = stb + ((size_t)tw * NT + ti) * STS;
    const unsigned short* Bb = stb + ((size_t)tw * NT + tj) * STS;

    f32x16 acc[4];
    #pragma unroll
    for (int b = 0; b < 4; ++b)
        #pragma unroll
        for (int e = 0; e < 16; ++e) acc[b][e] = 0.f;

    for (int ch = 0; ch < 10; ++ch) {
        __syncthreads();
        stageN(Al, Ab + ch * 8192, 4, wave, lane);
        stageN(Bl, Bb + ch * 8192, 4, wave, lane);
        __syncthreads();
        mfma_chunk64(Al, Bl, acc, rA, rB, lh);
    }

    const float inv = 1.0f / (HW - 1);
    unsigned short* cb = covb + ((size_t)tw * NPAIR + p) * 16384;
    #pragma unroll
    for (int b = 0; b < 4; ++b) {
        unsigned ow[8];
        #pragma unroll
        for (int wd = 0; wd < 8; ++wd)
            ow[wd] = (unsigned)f2bf(acc[b][2 * wd] * inv)
                   | ((unsigned)f2bf(acc[b][2 * wd + 1] * inv) << 16);
        size_t off = (size_t)((wave * 4 + b) * 64 + lane) * 16;
        *(uint4*)(cb + off)     = *(uint4*)&ow[0];
        *(uint4*)(cb + off + 8) = *(uint4*)&ow[4];
    }
}

// apply conv weight to an A-frag in registers (unpack bf16 -> fp32 mul -> repack RNE)
__device__ __forceinline__ bfrag8 weight_frag(bfrag8 a, const float* wf) {
    bfrag8 r;
    #pragma unroll
    for (int j = 0; j < 8; ++j) {
        float v = __uint_as_float(((unsigned)(unsigned short)a[j]) << 16);
        r[j] = (short)f2bf(v * wf[j]);
    }
    return r;
}

// weighted MFMA over ns s-iters; octbase = global octet offset of this LDS chunk
__device__ __forceinline__ void mfma_wchunk(const unsigned short* Al, const unsigned short* Bl,
                                            const float* wlf, f32x16* acc, int ns, int octbase,
                                            int rA, int rB, int lh) {
    #pragma unroll
    for (int s = 0; s < 4; ++s) {
        if (s >= ns) break;
        int oc = s * 2 + lh;
        const float* wf = &wlf[(octbase + oc) * 8];
        const unsigned short* ab = Al + (size_t)oc * 1024;
        const unsigned short* bb = Bl + (size_t)oc * 1024;
        bfrag8 a0 = weight_frag(*(const bfrag8*)&ab[rA * 8], wf);
        bfrag8 a1 = weight_frag(*(const bfrag8*)&ab[(rA + 32) * 8], wf);
        bfrag8 b0 = *(const bfrag8*)&bb[rB * 8];
        bfrag8 b1 = *(const bfrag8*)&bb[(rB + 32) * 8];
        acc[0] = __builtin_amdgcn_mfma_f32_32x32x16_bf16(a0, b0, acc[0], 0, 0, 0);
        acc[1] = __builtin_amdgcn_mfma_f32_32x32x16_bf16(a0, b1, acc[1], 0, 0, 0);
        acc[2] = __builtin_amdgcn_mfma_f32_32x32x16_bf16(a1, b0, acc[2], 0, 0, 0);
        acc[3] = __builtin_amdgcn_mfma_f32_32x32x16_bf16(a1, b1, acc[3], 0, 0, 0);
    }
}

// Fused M-build (weights in regs) + bf16 cov dot. grid = (p=15, qg=15, t=4).
__global__ __launch_bounds__(256, 3)
void score_kernel(const unsigned short* __restrict__ qtb, const unsigned short* __restrict__ covb,
                  const float* __restrict__ convw, float* __restrict__ out) {
    __shared__ unsigned short Al[8192], Bl[8192];
    __shared__ float wlf[QOCT * 8];
    __shared__ float red[4][WAY];
    int p = blockIdx.x, qg = blockIdx.y, t = blockIdx.z;
    int ti, tj; pair_ij(p, ti, tj);
    int tid = threadIdx.x, lane = tid & 63, wave = tid >> 6;
    int qm = wave & 1, qn = wave >> 1, lh = lane >> 5, ls = lane & 31;
    int rA = qm * 64 + ls, rB = qn * 64 + ls;
    bool diag = (ti == tj);
    float mult = diag ? 1.0f : 2.0f;
    const unsigned short* cbase = covb + ((size_t)(t * WAY) * NPAIR + p) * 16384;
    if (tid < QOCT * 8) wlf[tid] = (tid < HW) ? convw[tid] : 0.f;

    for (int qi = 0; qi < 5; ++qi) {
        int q = qg * 5 + qi;
        const unsigned short* Ab = qtb + ((size_t)(t * WQ + q) * NT + ti) * QTS;
        const unsigned short* Bb = qtb + ((size_t)(t * WQ + q) * NT + tj) * QTS;

        f32x16 acc[4];
        #pragma unroll
        for (int b = 0; b < 4; ++b)
            #pragma unroll
            for (int e = 0; e < 16; ++e) acc[b][e] = 0.f;

        // chunk 0: octets 0..7 (16 KB/plane)
        __syncthreads();                 // also orders wlf on first pass, red[] reuse
        stageN(Al, Ab, 4, wave, lane);
        if (!diag) stageN(Bl, Bb, 4, wave, lane);
        __syncthreads();
        mfma_wchunk(Al, diag ? Al : Bl, wlf, acc, 4, 0, rA, rB, lh);

        // chunk 1: octets 8..13 (12 KB/plane)
        __syncthreads();
        stageN(Al, Ab + 8192, 3, wave, lane);
        if (!diag) stageN(Bl, Bb + 8192, 3, wave, lane);
        __syncthreads();
        mfma_wchunk(Al, diag ? Al : Bl, wlf, acc, 3, 8, rA, rB, lh);

        // per-way dot + immediate reduce (no sums[] array -> no spill pressure)
        #pragma unroll 1
        for (int w = 0; w < WAY; ++w) {
            const unsigned short* cb = cbase + (size_t)w * NPAIR * 16384;
            float s = 0.f;
            #pragma unroll
            for (int b = 0; b < 4; ++b) {
                size_t off = (size_t)((wave * 4 + b) * 64 + lane) * 16;
                uint4 u0 = *(const uint4*)(cb + off);
                uint4 u1 = *(const uint4*)(cb + off + 8);
                unsigned uw[8] = {u0.x, u0.y, u0.z, u0.w, u1.x, u1.y, u1.z, u1.w};
                #pragma unroll
                for (int wd = 0; wd < 8; ++wd)
                    s += bflo(uw[wd]) * acc[b][2 * wd] + bfhi(uw[wd]) * acc[b][2 * wd + 1];
            }
            float v = s * mult;
            #pragma unroll
            for (int off2 = 32; off2 > 0; off2 >>= 1) v += __shfl_down(v, off2);
            if (lane == 0) red[wave][w] = v;
        }
        __syncthreads();
        if (tid < WAY) {
            float tot = red[0][tid] + red[1][tid] + red[2][tid] + red[3][tid];
            atomicAdd(&out[(size_t)(t * WQ + q) * WAY + tid], tot);
        }
    }
}

extern "C" void kernel_launch(void* const* d_in, const int* in_sizes, int n_in,
                              void* d_out, int out_size, void* d_ws, size_t ws_size,
                              hipStream_t stream) {
    const float* qf = (const float*)d_in[0];   // (4,75,640,10,10)
    const float* sf = (const float*)d_in[1];   // (4,25,640,10,10)
    const float* cw = (const float*)d_in[2];   // (1,1,100)
    const float* cb = (const float*)d_in[3];   // (1,)
    float* out = (float*)d_out;                // (4,75,5)

    unsigned short* covb = (unsigned short*)((char*)d_ws + WS_COVB_OFF);
    unsigned short* qtb  = (unsigned short*)((char*)d_ws + WS_QTB_OFF);
    unsigned short* stb  = (unsigned short*)((char*)d_ws + WS_STB_OFF);

    prep_kernel<<<3201, 256, 0, stream>>>(qf, sf, cb, qtb, stb, out);
    cov_kernel<<<dim3(NPAIR, T * WAY), 256, 0, stream>>>(stb, covb);
    score_kernel<<<dim3(NPAIR, WQ / 5, T), 256, 0, stream>>>(qtb, covb, cw, out);
}

// Round 9
// 278.494 us; speedup vs baseline: 2.9675x; 1.0223x over previous
//
#include <hip/hip_runtime.h>

// Problem constants
#define T     4
#define WQ    75
#define C     640
#define HW    100
#define WAY   5
#define SHOT  5
#define NT    5
#define NPAIR 15

// q tiles: [tq][tile(5)][oct(14)][row(128)][8] bf16; octet 12 half-zero, 13 zero
#define QOCT  14
#define QTS   (QOCT*128*8)        // 14336 shorts = 28 KB
// s tiles: [tw][tile(5)][oct(80)][row(128)][8] (16 oct/shot, zero-padded)
#define STS   81920

// ws layout (bytes)
#define WS_COVB_OFF  0            // 20*15*16384*2 = 9,830,400 (bf16, fragment order)
#define WS_QTB_OFF   9830400      // 300*5*14336*2 = 43,008,000
#define WS_QTBW_OFF  52838400     // 300*5*14336*2 = 43,008,000
#define WS_STB_OFF   95846400     // 20*5*81920*2  = 16,384,000

typedef __attribute__((ext_vector_type(8)))  short bfrag8;
typedef __attribute__((ext_vector_type(16))) float f32x16;

__device__ __forceinline__ unsigned short f2bf(float x) {
    unsigned int u = __float_as_uint(x);
    return (unsigned short)((u + 0x7fffu + ((u >> 16) & 1u)) >> 16);   // RNE
}
__device__ __forceinline__ float bflo(unsigned u) { return __uint_as_float(u << 16); }
__device__ __forceinline__ float bfhi(unsigned u) { return __uint_as_float(u & 0xffff0000u); }

__device__ __forceinline__ void pair_ij(int p, int& ti, int& tj) {
    int base = 0;
    #pragma unroll
    for (int a = 0; a < NT; ++a) {
        int cnt = NT - a;
        if (p < base + cnt) { ti = a; tj = a + (p - base); return; }
        base += cnt;
    }
    ti = 0; tj = 0;
}

// ---------- merged prep: out-init + qpack(+weighted) + spack ----------
// grid: [0,3000) qpack (cb=bid%10, tq=bid/10); [3000,3200) spack; 3200 init.
__global__ __launch_bounds__(256)
void prep_kernel(const float* __restrict__ qf, const float* __restrict__ sf,
                 const float* __restrict__ convw, const float* __restrict__ bias,
                 unsigned short* __restrict__ qtb, unsigned short* __restrict__ qtbw,
                 unsigned short* __restrict__ stb, float* __restrict__ out) {
    __shared__ float ld[64 * 101];
    __shared__ float wl[HW];
    __shared__ float mpart[64][4];
    __shared__ float mean[64];
    int bid = blockIdx.x, tid = threadIdx.x;

    if (bid < 3000) {
        int cb = bid % 10, tq = bid / 10;
        if (tid < HW) wl[tid] = convw[tid];
        const float* src = qf + ((size_t)tq * C + cb * 64) * HW;
        #pragma unroll
        for (int it = 0; it < 7; ++it) {
            int idx = tid + it * 256;
            if (idx < 1600) {
                float4 v = ((const float4*)src)[idx];
                int f = idx * 4;
                float vs[4] = {v.x, v.y, v.z, v.w};
                #pragma unroll
                for (int j = 0; j < 4; ++j) {
                    int ff = f + j;
                    ld[(ff / HW) * 101 + (ff % HW)] = vs[j];
                }
            }
        }
        __syncthreads();
        {
            int row = tid & 63, part = tid >> 6;
            float ps = 0.f;
            #pragma unroll
            for (int i = 0; i < 25; ++i) ps += ld[row * 101 + part * 25 + i];
            mpart[row][part] = ps;
        }
        __syncthreads();
        if (tid < 64) mean[tid] = (mpart[tid][0] + mpart[tid][1] + mpart[tid][2] + mpart[tid][3]) * (1.0f / HW);
        __syncthreads();
        int tile = cb >> 1, trowbase = (cb & 1) << 6;
        #pragma unroll
        for (int it = 0; it < 4; ++it) {
            int task = tid + it * 256;              // 896 tasks: row(64) x oct(14)
            if (task < 64 * QOCT) {
                int row = task & 63, oct = task >> 6;
                float m = mean[row];
                unsigned short ob[8] __attribute__((aligned(16)));
                unsigned short ow[8] __attribute__((aligned(16)));
                #pragma unroll
                for (int j = 0; j < 8; ++j) {
                    int n = oct * 8 + j;
                    float v = (n < HW) ? (ld[row * 101 + n] - m) : 0.f;
                    float w = (n < HW) ? wl[n] : 0.f;
                    ob[j] = f2bf(v); ow[j] = f2bf(v * w);
                }
                size_t dst = ((((size_t)tq * NT + tile) * QOCT + oct) * 128 + trowbase + row) * 8;
                *(uint4*)(qtb + dst)  = *(uint4*)ob;
                *(uint4*)(qtbw + dst) = *(uint4*)ow;
            }
        }
    } else if (bid < 3200) {
        int idx2 = bid - 3000;
        int cb = idx2 % 10, tw = idx2 / 10;
        int row = tid & 63, part = tid >> 6;
        float ps = 0.f;
        for (int sh = 0; sh < SHOT; ++sh) {
            const float* src = sf + ((size_t)(tw * SHOT + sh) * C + cb * 64) * HW;
            __syncthreads();
            #pragma unroll
            for (int it = 0; it < 7; ++it) {
                int idx = tid + it * 256;
                if (idx < 1600) {
                    float4 v = ((const float4*)src)[idx];
                    int f = idx * 4;
                    float vs[4] = {v.x, v.y, v.z, v.w};
                    #pragma unroll
                    for (int j = 0; j < 4; ++j) {
                        int ff = f + j;
                        ld[(ff / HW) * 101 + (ff % HW)] = vs[j];
                    }
                }
            }
            __syncthreads();
            #pragma unroll
            for (int i = 0; i < 25; ++i) ps += ld[row * 101 + part * 25 + i];
        }
        mpart[row][part] = ps;
        __syncthreads();
        if (tid < 64) mean[tid] = (mpart[tid][0] + mpart[tid][1] + mpart[tid][2] + mpart[tid][3]) * (1.0f / (SHOT * HW));
        int tile = cb >> 1, trowbase = (cb & 1) << 6;
        for (int sh = 0; sh < SHOT; ++sh) {
            const float* src = sf + ((size_t)(tw * SHOT + sh) * C + cb * 64) * HW;
            __syncthreads();
            #pragma unroll
            for (int it = 0; it < 7; ++it) {
                int idx = tid + it * 256;
                if (idx < 1600) {
                    float4 v = ((const float4*)src)[idx];
                    int f = idx * 4;
                    float vs[4] = {v.x, v.y, v.z, v.w};
                    #pragma unroll
                    for (int j = 0; j < 4; ++j) {
                        int ff = f + j;
                        ld[(ff / HW) * 101 + (ff % HW)] = vs[j];
                    }
                }
            }
            __syncthreads();
            #pragma unroll
            for (int it = 0; it < 4; ++it) {
                int task = tid + it * 256;
                int r2 = task & 63, oct = task >> 6;
                float m = mean[r2];
                unsigned short ob[8] __attribute__((aligned(16)));
                #pragma unroll
                for (int j = 0; j < 8; ++j) {
                    int n = oct * 8 + j;
                    ob[j] = (n < HW) ? f2bf(ld[r2 * 101 + n] - m) : (unsigned short)0;
                }
                size_t dst = ((((size_t)tw * NT + tile) * 80 + sh * 16 + oct) * 128 + trowbase + r2) * 8;
                *(uint4*)(stb + dst) = *(uint4*)ob;
            }
        }
    } else {
        float b = bias[0];
        for (int i = tid; i < T * WQ * WAY; i += 256) out[i] = b;
    }
}

// ---------- cov: direct global->VGPR fragment loads, no LDS, no barriers ----------
// grid = (NPAIR, T*WAY). stb per tw (819 KB) is read by 15 blocks -> L2-resident.
__global__ __launch_bounds__(256, 3)
void cov_kernel(const unsigned short* __restrict__ stb, unsigned short* __restrict__ covb) {
    int p = blockIdx.x, tw = blockIdx.y;
    int ti, tj; pair_ij(p, ti, tj);
    int tid = threadIdx.x, lane = tid & 63, wave = tid >> 6;
    int qm = wave & 1, qn = wave >> 1, lh = lane >> 5, ls = lane & 31;
    int rA = qm * 64 + ls, rB = qn * 64 + ls;
    const unsigned short* Ab = stb + ((size_t)tw * NT + ti) * STS;
    const unsigned short* Bb = stb + ((size_t)tw * NT + tj) * STS;

    f32x16 acc[4];
    #pragma unroll
    for (int b = 0; b < 4; ++b)
        #pragma unroll
        for (int e = 0; e < 16; ++e) acc[b][e] = 0.f;

    #pragma unroll 4
    for (int s = 0; s < 40; ++s) {
        int oc = s * 2 + lh;
        const unsigned short* ap = Ab + (size_t)oc * 1024;
        const unsigned short* bp = Bb + (size_t)oc * 1024;
        bfrag8 a0 = *(const bfrag8*)&ap[rA * 8];
        bfrag8 a1 = *(const bfrag8*)&ap[(rA + 32) * 8];
        bfrag8 b0 = *(const bfrag8*)&bp[rB * 8];
        bfrag8 b1 = *(const bfrag8*)&bp[(rB + 32) * 8];
        acc[0] = __builtin_amdgcn_mfma_f32_32x32x16_bf16(a0, b0, acc[0], 0, 0, 0);
        acc[1] = __builtin_amdgcn_mfma_f32_32x32x16_bf16(a0, b1, acc[1], 0, 0, 0);
        acc[2] = __builtin_amdgcn_mfma_f32_32x32x16_bf16(a1, b0, acc[2], 0, 0, 0);
        acc[3] = __builtin_amdgcn_mfma_f32_32x32x16_bf16(a1, b1, acc[3], 0, 0, 0);
    }

    const float inv = 1.0f / (HW - 1);
    unsigned short* cb = covb + ((size_t)tw * NPAIR + p) * 16384;
    #pragma unroll
    for (int b = 0; b < 4; ++b) {
        unsigned ow[8];
        #pragma unroll
        for (int wd = 0; wd < 8; ++wd)
            ow[wd] = (unsigned)f2bf(acc[b][2 * wd] * inv)
                   | ((unsigned)f2bf(acc[b][2 * wd + 1] * inv) << 16);
        size_t off = (size_t)((wave * 4 + b) * 64 + lane) * 16;
        *(uint4*)(cb + off)     = *(uint4*)&ow[0];
        *(uint4*)(cb + off + 8) = *(uint4*)&ow[4];
    }
}

// ---------- score: direct-register gram (no LDS/barriers) + bf16 cov dot ----------
// grid = (p=15, qg=15, t=4); A from pre-weighted qtbw, B from qtb.
__global__ __launch_bounds__(256, 3)
void score_kernel(const unsigned short* __restrict__ qtb, const unsigned short* __restrict__ qtbw,
                  const unsigned short* __restrict__ covb, float* __restrict__ out) {
    __shared__ float red[4][WAY];
    int p = blockIdx.x, qg = blockIdx.y, t = blockIdx.z;
    int ti, tj; pair_ij(p, ti, tj);
    int tid = threadIdx.x, lane = tid & 63, wave = tid >> 6;
    int qm = wave & 1, qn = wave >> 1, lh = lane >> 5, ls = lane & 31;
    int rA = qm * 64 + ls, rB = qn * 64 + ls;
    float mult = (ti == tj) ? 1.0f : 2.0f;
    const unsigned short* cbase = covb + ((size_t)(t * WAY) * NPAIR + p) * 16384;

    for (int qi = 0; qi < 5; ++qi) {
        int q = qg * 5 + qi;
        const unsigned short* Ab = qtbw + ((size_t)(t * WQ + q) * NT + ti) * QTS;
        const unsigned short* Bb = qtb  + ((size_t)(t * WQ + q) * NT + tj) * QTS;

        f32x16 acc[4];
        #pragma unroll
        for (int b = 0; b < 4; ++b)
            #pragma unroll
            for (int e = 0; e < 16; ++e) acc[b][e] = 0.f;

        #pragma unroll
        for (int s = 0; s < 7; ++s) {
            int oc = s * 2 + lh;
            const unsigned short* ap = Ab + (size_t)oc * 1024;
            const unsigned short* bp = Bb + (size_t)oc * 1024;
            bfrag8 a0 = *(const bfrag8*)&ap[rA * 8];
            bfrag8 a1 = *(const bfrag8*)&ap[(rA + 32) * 8];
            bfrag8 b0 = *(const bfrag8*)&bp[rB * 8];
            bfrag8 b1 = *(const bfrag8*)&bp[(rB + 32) * 8];
            acc[0] = __builtin_amdgcn_mfma_f32_32x32x16_bf16(a0, b0, acc[0], 0, 0, 0);
            acc[1] = __builtin_amdgcn_mfma_f32_32x32x16_bf16(a0, b1, acc[1], 0, 0, 0);
            acc[2] = __builtin_amdgcn_mfma_f32_32x32x16_bf16(a1, b0, acc[2], 0, 0, 0);
            acc[3] = __builtin_amdgcn_mfma_f32_32x32x16_bf16(a1, b1, acc[3], 0, 0, 0);
        }

        // per-way Frobenius dot + immediate reduce (no sums[] array)
        #pragma unroll 1
        for (int w = 0; w < WAY; ++w) {
            const unsigned short* cb = cbase + (size_t)w * NPAIR * 16384;
            float s = 0.f;
            #pragma unroll
            for (int b = 0; b < 4; ++b) {
                size_t off = (size_t)((wave * 4 + b) * 64 + lane) * 16;
                uint4 u0 = *(const uint4*)(cb + off);
                uint4 u1 = *(const uint4*)(cb + off + 8);
                unsigned uw[8] = {u0.x, u0.y, u0.z, u0.w, u1.x, u1.y, u1.z, u1.w};
                #pragma unroll
                for (int wd = 0; wd < 8; ++wd)
                    s += bflo(uw[wd]) * acc[b][2 * wd] + bfhi(uw[wd]) * acc[b][2 * wd + 1];
            }
            float v = s * mult;
            #pragma unroll
            for (int off2 = 32; off2 > 0; off2 >>= 1) v += __shfl_down(v, off2);
            if (lane == 0) red[wave][w] = v;
        }
        __syncthreads();
        if (tid < WAY) {
            float tot = red[0][tid] + red[1][tid] + red[2][tid] + red[3][tid];
            atomicAdd(&out[(size_t)(t * WQ + q) * WAY + tid], tot);
        }
        __syncthreads();                 // red[] consumed before next query overwrites
    }
}

extern "C" void kernel_launch(void* const* d_in, const int* in_sizes, int n_in,
                              void* d_out, int out_size, void* d_ws, size_t ws_size,
                              hipStream_t stream) {
    const float* qf = (const float*)d_in[0];   // (4,75,640,10,10)
    const float* sf = (const float*)d_in[1];   // (4,25,640,10,10)
    const float* cw = (const float*)d_in[2];   // (1,1,100)
    const float* cb = (const float*)d_in[3];   // (1,)
    float* out = (float*)d_out;                // (4,75,5)

    unsigned short* covb = (unsigned short*)((char*)d_ws + WS_COVB_OFF);
    unsigned short* qtb  = (unsigned short*)((char*)d_ws + WS_QTB_OFF);
    unsigned short* qtbw = (unsigned short*)((char*)d_ws + WS_QTBW_OFF);
    unsigned short* stb  = (unsigned short*)((char*)d_ws + WS_STB_OFF);

    prep_kernel<<<3201, 256, 0, stream>>>(qf, sf, cw, cb, qtb, qtbw, stb, out);
    cov_kernel<<<dim3(NPAIR, T * WAY), 256, 0, stream>>>(stb, covb);
    score_kernel<<<dim3(NPAIR, WQ / 5, T), 256, 0, stream>>>(qtb, qtbw, covb, out);
}